// Round 10
// baseline (855.703 us; speedup 1.0000x reference)
//
#include <hip/hip_runtime.h>
#include <math.h>

// Problem constants (match reference)
#define Bb   256
#define Tt   512
#define Vv   50000
#define Ee   300
#define Hh   128
#define G4   512          // 4*H
#define EPS  1e-12f
#define FBIAS 1.0f

typedef _Float16 half8 __attribute__((ext_vector_type(8)));
typedef float    f32x4 __attribute__((ext_vector_type(4)));

// ---------------------------------------------------------------------------
// Cross-lane helpers (DPP-only reductions)
// ---------------------------------------------------------------------------
template <int CTRL>
__device__ inline float dpp_mov(float v) {
    return __int_as_float(
        __builtin_amdgcn_update_dpp(0, __float_as_int(v), CTRL, 0xF, 0xF, true));
}
__device__ inline float red16(float v) {
    v += dpp_mov<0xB1>(v);    // quad_perm [1,0,3,2]
    v += dpp_mov<0x4E>(v);    // quad_perm [2,3,0,1]
    v += dpp_mov<0x141>(v);   // row_half_mirror
    v += dpp_mov<0x140>(v);   // row_mirror
    return v;
}
__device__ inline float red64b(float v) {
    v = red16(v);
    v += dpp_mov<0x142>(v);   // row_bcast15
    v += dpp_mov<0x143>(v);   // row_bcast31  => lane63 holds total
    return __int_as_float(__builtin_amdgcn_readlane(__float_as_int(v), 63));
}

// LDS-only barrier: drain lgkmcnt, raw s_barrier (vm prefetches float across)
__device__ inline void lds_barrier() {
    asm volatile("s_waitcnt lgkmcnt(0)" ::: "memory");
    __builtin_amdgcn_s_barrier();
}

__device__ inline float sigm(float v) {
    return __fdividef(1.0f, 1.0f + __expf(-v));
}

// ---------------------------------------------------------------------------
// Phase 1: P[v,:] = embed[v,:] @ W[0:E,:] via f16 MFMA, staged-LDS A
// (round-7/8 proven version). P stored f16.
// ---------------------------------------------------------------------------
#define PROJ_TILES ((Vv + 31) / 32)

__global__ __launch_bounds__(512, 2) void embed_proj_mfma(
    const float* __restrict__ embed,   // [V, E]
    const float* __restrict__ W,       // [E+H, 4H]
    _Float16* __restrict__ P)          // [V, 4H] f16
{
    __shared__ __align__(16) _Float16 A[32 * 320];   // 20 KB

    const int tid  = threadIdx.x;
    const int wv   = tid >> 6;
    const int lane = tid & 63;
    const int p16  = lane & 15;
    const int gq   = lane >> 4;

    half8 bf[4][10];
    #pragma unroll
    for (int tt = 0; tt < 4; ++tt) {
        #pragma unroll
        for (int ks = 0; ks < 10; ++ks) {
            half8 h;
            #pragma unroll
            for (int j = 0; j < 8; ++j) {
                int k = ks * 32 + gq * 8 + j;
                h[j] = (k < Ee)
                     ? (_Float16)W[(size_t)k * G4 + wv * 64 + tt * 16 + p16]
                     : (_Float16)0.f;
            }
            bf[tt][ks] = h;
        }
    }

    char* const Ab = (char*)A;
    for (int i = tid; i < 32 * 10; i += 512) {
        int row = i / 10, m = i - row * 10;
        *(uint*)(Ab + ((row * 640 + 600 + m * 4) ^ ((row & 7) << 4))) = 0u;
    }
    __syncthreads();

    for (int mtile = blockIdx.x; mtile < PROJ_TILES; mtile += gridDim.x) {
        const int r0 = mtile * 32;

        for (int i = tid; i < 32 * 75; i += 512) {
            int row = i / 75, k4 = i - row * 75;
            int grow = r0 + row;
            float4 v = (grow < Vv) ? *(const float4*)&embed[(size_t)grow * Ee + k4 * 4]
                                   : (float4){0.f, 0.f, 0.f, 0.f};
            union { _Float16 h[4]; uint2 u; } pk;
            pk.h[0] = (_Float16)v.x; pk.h[1] = (_Float16)v.y;
            pk.h[2] = (_Float16)v.z; pk.h[3] = (_Float16)v.w;
            *(uint2*)(Ab + ((row * 640 + k4 * 8) ^ ((row & 7) << 4))) = pk.u;
        }
        __syncthreads();

        f32x4 acc[2][4];
        #pragma unroll
        for (int mt = 0; mt < 2; ++mt)
            #pragma unroll
            for (int tt = 0; tt < 4; ++tt)
                acc[mt][tt] = (f32x4){0.f, 0.f, 0.f, 0.f};

        #pragma unroll
        for (int mt = 0; mt < 2; ++mt) {
            const int arow = mt * 16 + p16;
            #pragma unroll
            for (int ks = 0; ks < 10; ++ks) {
                half8 af = *(const half8*)(Ab + ((arow * 640 + ks * 64 + gq * 16)
                                                 ^ ((arow & 7) << 4)));
                #pragma unroll
                for (int tt = 0; tt < 4; ++tt)
                    acc[mt][tt] = __builtin_amdgcn_mfma_f32_16x16x32_f16(
                        af, bf[tt][ks], acc[mt][tt], 0, 0, 0);
            }
        }

        #pragma unroll
        for (int mt = 0; mt < 2; ++mt)
            #pragma unroll
            for (int tt = 0; tt < 4; ++tt)
                #pragma unroll
                for (int r = 0; r < 4; ++r) {
                    int row = r0 + mt * 16 + gq * 4 + r;
                    if (row < Vv)
                        P[(size_t)row * G4 + wv * 64 + tt * 16 + p16] =
                            (_Float16)acc[mt][tt][r];
                }
        __syncthreads();
    }
}

// ---------------------------------------------------------------------------
// Phase 2: 64 blocks x 4 rows x 8 waves (512 thr), 2 lgkm-barriers per step.
// Round-9 structure +:
//  - MFMA accumulator C-initialized with P (prefetched as 16 ushort, 2 steps
//    ahead) -> M-phase acc holds FINAL z
//  - M phase computes per-wave s/q gate partials (4 adds + 8 red16) into a
//    256B LDS table riding barrier 1
//  - L phase: no P unpack, no q red64b, no readlane mean machinery; reads 16
//    broadcast floats for all gate stats. Only cell-LN needs red64b.
//  - Wsum/Psum kernels deleted.
// ---------------------------------------------------------------------------
#define RPBLK 4
#define LBLK  (Bb / RPBLK)   // 64 blocks

#define PLOAD(PM, TI)                                                          \
{                                                                              \
    const int ti_ = (TI) < Tt ? (TI) : Tt - 1;                                 \
    const int a0 = xtok[0][ti_], a1 = xtok[1][ti_];                            \
    const int a2 = xtok[2][ti_], a3 = xtok[3][ti_];                            \
    const unsigned short* Pu = (const unsigned short*)P;                       \
    const unsigned short* b0 = Pu + (size_t)a0 * G4 + wv * 64 + p16;           \
    const unsigned short* b1 = Pu + (size_t)a1 * G4 + wv * 64 + p16;           \
    const unsigned short* b2 = Pu + (size_t)a2 * G4 + wv * 64 + p16;           \
    const unsigned short* b3 = Pu + (size_t)a3 * G4 + wv * 64 + p16;           \
    _Pragma("unroll")                                                          \
    for (int tt = 0; tt < 4; ++tt) {                                           \
        PM[0 * 4 + tt] = b0[tt * 16];                                          \
        PM[1 * 4 + tt] = b1[tt * 16];                                          \
        PM[2 * 4 + tt] = b2[tt * 16];                                          \
        PM[3 * 4 + tt] = b3[tt * 16];                                          \
    }                                                                          \
}

#define LSTM_STEP(TSTEP, PM)                                                   \
{                                                                              \
    /* ---- M phase (all 8 waves): z = P + h@Wh, stage z + s/q partials ---- */\
    {                                                                          \
        half8 af[4];                                                           \
        _Pragma("unroll")                                                      \
        for (int ks = 0; ks < 4; ++ks)                                         \
            af[ks] = *(const half8*)(hb + p16 * 256 +                          \
                         ((ks * 64 + (gq << 4)) ^ ((p16 & 7) << 4)));          \
        f32x4 acc[4];                                                          \
        _Pragma("unroll")                                                      \
        for (int tt = 0; tt < 4; ++tt) {                                       \
            f32x4 a;                                                           \
            _Pragma("unroll")                                                  \
            for (int r = 0; r < 4; ++r) {                                      \
                unsigned short u = (unsigned short)PM[r * 4 + tt];             \
                float pv = (float)__builtin_bit_cast(_Float16, u);             \
                a[r] = (lane < 16) ? pv : 0.f;                                 \
            }                                                                  \
            acc[tt] = a;                                                       \
        }                                                                      \
        _Pragma("unroll")                                                      \
        for (int tt = 0; tt < 4; ++tt) {                                       \
            _Pragma("unroll")                                                  \
            for (int ks = 0; ks < 4; ++ks)                                     \
                acc[tt] = __builtin_amdgcn_mfma_f32_16x16x32_f16(              \
                    af[ks], bfrag[tt][ks], acc[tt], 0, 0, 0);                  \
        }                                                                      \
        /* reload PM for step TSTEP+2 (consumed 2 steps from now) */           \
        PLOAD(PM, (TSTEP) + 2)                                                 \
        /* z stage (lanes 0-15 hold rows 0-3) */                               \
        if (lane < 16) {                                                       \
            _Pragma("unroll")                                                  \
            for (int tt = 0; tt < 4; ++tt) {                                   \
                const int col = wv * 64 + tt * 16 + p16;                       \
                _Pragma("unroll")                                              \
                for (int r = 0; r < 4; ++r) z_lds[r][col] = acc[tt][r];        \
            }                                                                  \
        }                                                                      \
        /* s/q partials over this wave's 64 cols (one gate) per row */         \
        {                                                                      \
            float sA[4], qA[4];                                                \
            _Pragma("unroll")                                                  \
            for (int r = 0; r < 4; ++r) {                                      \
                float s = (acc[0][r] + acc[1][r]) + (acc[2][r] + acc[3][r]);   \
                float q = acc[0][r] * acc[0][r];                               \
                q = fmaf(acc[1][r], acc[1][r], q);                             \
                q = fmaf(acc[2][r], acc[2][r], q);                             \
                q = fmaf(acc[3][r], acc[3][r], q);                             \
                sA[r] = red16(s); qA[r] = red16(q);                            \
            }                                                                  \
            float ws = sA[0], wq = qA[0];                                      \
            ws = (p16 == 1) ? sA[1] : ws;  wq = (p16 == 1) ? qA[1] : wq;       \
            ws = (p16 == 2) ? sA[2] : ws;  wq = (p16 == 2) ? qA[2] : wq;       \
            ws = (p16 == 3) ? sA[3] : ws;  wq = (p16 == 3) ? qA[3] : wq;       \
            if (lane < 4) *(float2*)&part[lane][wv][0] = (float2){ws, wq};     \
        }                                                                      \
    }                                                                          \
    lds_barrier();   /* z + partials staged */                                 \
    /* ---- L phase: waves 0-3, row wv, hdims 2*lane, 2*lane+1 ---- */         \
    if (wv < 4) {                                                              \
        float2 zi[4];                                                          \
        _Pragma("unroll")                                                      \
        for (int g = 0; g < 4; ++g)                                            \
            zi[g] = *(const float2*)&z_lds[wv][g * 128 + 2 * lane];            \
        const float4 pt0 = *(const float4*)&part[wv][0][0];                    \
        const float4 pt1 = *(const float4*)&part[wv][2][0];                    \
        const float4 pt2 = *(const float4*)&part[wv][4][0];                    \
        const float4 pt3 = *(const float4*)&part[wv][6][0];                    \
        float mean[4], rstd[4];                                                \
        {                                                                      \
            float st, qt;                                                      \
            st = pt0.x + pt0.z; qt = pt0.y + pt0.w;                            \
            mean[0] = st * (1.0f / Hh);                                        \
            rstd[0] = rsqrtf(qt * (1.0f / Hh) - mean[0] * mean[0] + EPS);      \
            st = pt1.x + pt1.z; qt = pt1.y + pt1.w;                            \
            mean[1] = st * (1.0f / Hh);                                        \
            rstd[1] = rsqrtf(qt * (1.0f / Hh) - mean[1] * mean[1] + EPS);      \
            st = pt2.x + pt2.z; qt = pt2.y + pt2.w;                            \
            mean[2] = st * (1.0f / Hh);                                        \
            rstd[2] = rsqrtf(qt * (1.0f / Hh) - mean[2] * mean[2] + EPS);      \
            st = pt3.x + pt3.z; qt = pt3.y + pt3.w;                            \
            mean[3] = st * (1.0f / Hh);                                        \
            rstd[3] = rsqrtf(qt * (1.0f / Hh) - mean[3] * mean[3] + EPS);      \
        }                                                                      \
        float2 nv[4];                                                          \
        _Pragma("unroll")                                                      \
        for (int g = 0; g < 4; ++g) {                                          \
            const float ax = rstd[g] * gg[g].x, ay = rstd[g] * gg[g].y;        \
            const float bx = sg[g].x - mean[g] * ax;                           \
            const float by = sg[g].y - mean[g] * ay;                           \
            nv[g].x = fmaf(zi[g].x, ax, bx);                                   \
            nv[g].y = fmaf(zi[g].y, ay, by);                                   \
        }                                                                      \
        const float sox = sigm(nv[3].x);                                       \
        const float soy = sigm(nv[3].y);                                       \
        c0 = c0 * sigm(nv[2].x + FBIAS) + sigm(nv[0].x) * fmaxf(nv[1].x, 0.f); \
        c1 = c1 * sigm(nv[2].y + FBIAS) + sigm(nv[0].y) * fmaxf(nv[1].y, 0.f); \
        float s2 = red64b(c0 + c1);                                            \
        float q2 = red64b(fmaf(c0, c0, c1 * c1));                              \
        const float m2 = s2 * (1.0f / Hh);                                     \
        const float v2 = q2 * (1.0f / Hh) - m2 * m2;                           \
        const float r2 = rsqrtf(v2 + EPS);                                     \
        const float lc0 = (c0 - m2) * r2 * gcell.x + scell.x;                  \
        const float lc1 = (c1 - m2) * r2 * gcell.y + scell.y;                  \
        const float h0 = fmaxf(lc0, 0.f) * sox;                                \
        const float h1 = fmaxf(lc1, 0.f) * soy;                                \
        {                                                                      \
            union { _Float16 hh2[2]; uint u; } pk;                             \
            pk.hh2[0] = (_Float16)h0; pk.hh2[1] = (_Float16)h1;                \
            *(uint*)(hb + wv * 256 + ((4 * lane) ^ ((wv & 7) << 4))) = pk.u;   \
        }                                                                      \
        *(float2*)&out[((size_t)row_g * Tt + (TSTEP)) * Hh + 2 * lane] =       \
            (float2){h0, h1};                                                  \
    }                                                                          \
    lds_barrier();   /* h ready */                                             \
}

__global__ __launch_bounds__(512, 1) void lstm_mfma8(
    const _Float16* __restrict__ P,    // [V, 4H] f16
    const float* __restrict__ W,       // [E+H, 4H]
    const int*   __restrict__ x,       // [B, T]
    const float* __restrict__ gains,   // [5, H]
    const float* __restrict__ shifts,  // [5, H]
    float* __restrict__ out)           // [B, T, H]
{
    __shared__ __align__(16) float    z_lds[RPBLK][G4];   // 8 KB
    __shared__ __align__(16) _Float16 h_lds[16][Hh];      // 4 KB (swizzled)
    __shared__ __align__(16) int      xtok[RPBLK][Tt];    // 8 KB
    __shared__ __align__(16) float    part[RPBLK][8][2];  // 256 B  s/q partials

    const int tid  = threadIdx.x;
    const int wv   = tid >> 6;         // 0..7: MFMA col-slice; <4: L row
    const int lane = tid & 63;
    const int gq   = lane >> 4;
    const int p16  = lane & 15;
    const int bb   = blockIdx.x;

    // stage tokens for this block's 4 rows (2048 ints = 512 int4)
    {
        const int4* xs = (const int4*)(x + (size_t)bb * RPBLK * Tt);
        ((int4*)&xtok[0][0])[tid] = xs[tid];
    }
    // zero h tile
    {
        uint* hz = (uint*)h_lds;
        hz[tid] = 0u; hz[tid + 512] = 0u;
    }

    // Wh B-fragments: cols wv*64 + tt*16 + p16
    half8 bfrag[4][4];
    #pragma unroll
    for (int tt = 0; tt < 4; ++tt) {
        #pragma unroll
        for (int ks = 0; ks < 4; ++ks) {
            half8 h;
            #pragma unroll
            for (int j = 0; j < 8; ++j) {
                h[j] = (_Float16)W[(size_t)(Ee + ks * 32 + gq * 8 + j) * G4
                                   + wv * 64 + tt * 16 + p16];
            }
            bfrag[tt][ks] = h;
        }
    }

    // LN params (used by waves 0-3; in-bounds for all)
    float2 gg[4], sg[4];
    #pragma unroll
    for (int g = 0; g < 4; ++g) {
        gg[g] = *(const float2*)&gains[g * Hh + 2 * lane];
        sg[g] = *(const float2*)&shifts[g * Hh + 2 * lane];
    }
    const float2 gcell = *(const float2*)&gains[4 * Hh + 2 * lane];
    const float2 scell = *(const float2*)&shifts[4 * Hh + 2 * lane];

    const int row_g = bb * RPBLK + (wv & 3);

    float c0 = 0.f, c1 = 0.f;
    char* const hb = (char*)h_lds;

    __syncthreads();   // tokens + h staged

    // Prologue: P loads for steps 0 (pmA) and 1 (pmB)
    uint pmA[16], pmB[16];
    PLOAD(pmA, 0)
    PLOAD(pmB, 1)

    for (int t = 0; t < Tt; t += 2) {
        LSTM_STEP(t,     pmA)
        LSTM_STEP(t + 1, pmB)
    }
}

// ---------------------------------------------------------------------------
extern "C" void kernel_launch(void* const* d_in, const int* in_sizes, int n_in,
                              void* d_out, int out_size, void* d_ws, size_t ws_size,
                              hipStream_t stream) {
    const int*   x      = (const int*)d_in[0];
    const float* embed  = (const float*)d_in[1];
    const float* W      = (const float*)d_in[2];
    const float* gains  = (const float*)d_in[3];
    const float* shifts = (const float*)d_in[4];
    float* out = (float*)d_out;

    _Float16* P = (_Float16*)d_ws;   // [V, 4H] f16 = 51.2 MB

    embed_proj_mfma<<<dim3(256), dim3(512), 0, stream>>>(embed, W, P);
    lstm_mfma8<<<dim3(LBLK), dim3(512), 0, stream>>>(P, W, x, gains, shifts, out);
}

// Round 11
// 722.223 us; speedup vs baseline: 1.1848x; 1.1848x over previous
//
#include <hip/hip_runtime.h>
#include <math.h>

// Problem constants (match reference)
#define Bb   256
#define Tt   512
#define Vv   50000
#define Ee   300
#define Hh   128
#define G4   512          // 4*H
#define EPS  1e-12f
#define FBIAS 1.0f

typedef _Float16 half8 __attribute__((ext_vector_type(8)));
typedef float    f32x4 __attribute__((ext_vector_type(4)));

// ---------------------------------------------------------------------------
// Cross-lane helpers (DPP-only reductions)
// ---------------------------------------------------------------------------
template <int CTRL>
__device__ inline float dpp_mov(float v) {
    return __int_as_float(
        __builtin_amdgcn_update_dpp(0, __float_as_int(v), CTRL, 0xF, 0xF, true));
}
__device__ inline float red16(float v) {
    v += dpp_mov<0xB1>(v);    // quad_perm [1,0,3,2]
    v += dpp_mov<0x4E>(v);    // quad_perm [2,3,0,1]
    v += dpp_mov<0x141>(v);   // row_half_mirror
    v += dpp_mov<0x140>(v);   // row_mirror
    return v;
}
__device__ inline float red64b(float v) {
    v = red16(v);
    v += dpp_mov<0x142>(v);   // row_bcast15
    v += dpp_mov<0x143>(v);   // row_bcast31  => lane63 holds total
    return __int_as_float(__builtin_amdgcn_readlane(__float_as_int(v), 63));
}

// LDS-only barrier: drain lgkmcnt, raw s_barrier (vm prefetches float across)
__device__ inline void lds_barrier() {
    asm volatile("s_waitcnt lgkmcnt(0)" ::: "memory");
    __builtin_amdgcn_s_barrier();
}

__device__ inline float sigm(float v) {
    return __fdividef(1.0f, 1.0f + __expf(-v));
}

// ---------------------------------------------------------------------------
// Phase 1: P[v,:] = embed[v,:] @ W[0:E,:] via f16 MFMA, staged-LDS A
// (round-7/8 proven version) + fused Psum epilogue (round-9 proven piece).
// ---------------------------------------------------------------------------
#define PROJ_TILES ((Vv + 31) / 32)

__global__ __launch_bounds__(512, 2) void embed_proj_mfma(
    const float* __restrict__ embed,   // [V, E]
    const float* __restrict__ W,       // [E+H, 4H]
    _Float16* __restrict__ P,          // [V, 4H] f16
    float* __restrict__ Psum)          // [V, 4] f32
{
    __shared__ __align__(16) _Float16 A[32 * 320];   // 20 KB
    __shared__ float part[32][8];

    const int tid  = threadIdx.x;
    const int wv   = tid >> 6;
    const int lane = tid & 63;
    const int p16  = lane & 15;
    const int gq   = lane >> 4;

    half8 bf[4][10];
    #pragma unroll
    for (int tt = 0; tt < 4; ++tt) {
        #pragma unroll
        for (int ks = 0; ks < 10; ++ks) {
            half8 h;
            #pragma unroll
            for (int j = 0; j < 8; ++j) {
                int k = ks * 32 + gq * 8 + j;
                h[j] = (k < Ee)
                     ? (_Float16)W[(size_t)k * G4 + wv * 64 + tt * 16 + p16]
                     : (_Float16)0.f;
            }
            bf[tt][ks] = h;
        }
    }

    char* const Ab = (char*)A;
    for (int i = tid; i < 32 * 10; i += 512) {
        int row = i / 10, m = i - row * 10;
        *(uint*)(Ab + ((row * 640 + 600 + m * 4) ^ ((row & 7) << 4))) = 0u;
    }
    __syncthreads();

    for (int mtile = blockIdx.x; mtile < PROJ_TILES; mtile += gridDim.x) {
        const int r0 = mtile * 32;

        for (int i = tid; i < 32 * 75; i += 512) {
            int row = i / 75, k4 = i - row * 75;
            int grow = r0 + row;
            float4 v = (grow < Vv) ? *(const float4*)&embed[(size_t)grow * Ee + k4 * 4]
                                   : (float4){0.f, 0.f, 0.f, 0.f};
            union { _Float16 h[4]; uint2 u; } pk;
            pk.h[0] = (_Float16)v.x; pk.h[1] = (_Float16)v.y;
            pk.h[2] = (_Float16)v.z; pk.h[3] = (_Float16)v.w;
            *(uint2*)(Ab + ((row * 640 + k4 * 8) ^ ((row & 7) << 4))) = pk.u;
        }
        __syncthreads();

        f32x4 acc[2][4];
        #pragma unroll
        for (int mt = 0; mt < 2; ++mt)
            #pragma unroll
            for (int tt = 0; tt < 4; ++tt)
                acc[mt][tt] = (f32x4){0.f, 0.f, 0.f, 0.f};

        #pragma unroll
        for (int mt = 0; mt < 2; ++mt) {
            const int arow = mt * 16 + p16;
            #pragma unroll
            for (int ks = 0; ks < 10; ++ks) {
                half8 af = *(const half8*)(Ab + ((arow * 640 + ks * 64 + gq * 16)
                                                 ^ ((arow & 7) << 4)));
                #pragma unroll
                for (int tt = 0; tt < 4; ++tt)
                    acc[mt][tt] = __builtin_amdgcn_mfma_f32_16x16x32_f16(
                        af, bf[tt][ks], acc[mt][tt], 0, 0, 0);
            }
        }

        // P store: row = r0 + mt*16 + gq*4 + r ; col = wv*64 + tt*16 + p16
        #pragma unroll
        for (int mt = 0; mt < 2; ++mt)
            #pragma unroll
            for (int tt = 0; tt < 4; ++tt)
                #pragma unroll
                for (int r = 0; r < 4; ++r) {
                    int row = r0 + mt * 16 + gq * 4 + r;
                    if (row < Vv)
                        P[(size_t)row * G4 + wv * 64 + tt * 16 + p16] =
                            (_Float16)acc[mt][tt][r];
                }

        // Psum partials: wave's 64 cols (one half-gate) summed per row
        #pragma unroll
        for (int mt = 0; mt < 2; ++mt) {
            #pragma unroll
            for (int r = 0; r < 4; ++r) {
                float s = (acc[mt][0][r] + acc[mt][1][r])
                        + (acc[mt][2][r] + acc[mt][3][r]);
                s = red16(s);
                if (p16 == 0) part[mt * 16 + gq * 4 + r][wv] = s;
            }
        }
        __syncthreads();
        if (tid < 128) {
            int row = tid >> 2, g = tid & 3;
            if (r0 + row < Vv)
                Psum[(size_t)(r0 + row) * 4 + g] = part[row][2 * g]
                                                 + part[row][2 * g + 1];
        }
        __syncthreads();   // part + A reads done before restage
    }
}

// ---------------------------------------------------------------------------
// Wsum[k][g] = sum over gate g's 128 cols of W[Ee+k][*]   (128 x 4 f32)
// ---------------------------------------------------------------------------
__global__ __launch_bounds__(128) void wsum_kernel(
    const float* __restrict__ W, float* __restrict__ Wsum)
{
    const int k = threadIdx.x;          // 0..127
    const float* wr = W + (size_t)(Ee + k) * G4;
    #pragma unroll
    for (int g = 0; g < 4; ++g) {
        float s = 0.f;
        for (int c = 0; c < 128; c += 4) {
            float4 v = *(const float4*)&wr[g * 128 + c];
            s += (v.x + v.y) + (v.z + v.w);
        }
        Wsum[k * 4 + g] = s;
    }
}

// ---------------------------------------------------------------------------
// Phase 2: round-9 lstm_mfma7 VERBATIM (measured best: 608 us).
// 64 blocks x 4 rows x 8 waves (512 thr), 2 lgkm-barriers per step.
// ---------------------------------------------------------------------------
#define RPBLK 4
#define LBLK  (Bb / RPBLK)   // 64 blocks

#define LSTM_STEP(TSTEP, PC, QC, PL, QL)                                       \
{                                                                              \
    /* ---- M phase ---- */                                                    \
    if (wv < 4) {  /* issue P prefetch for TSTEP+3 (token tkR) */              \
        const _Float16* pr = P + (size_t)tkR * G4;                             \
        _Pragma("unroll")                                                      \
        for (int g = 0; g < 4; ++g)                                            \
            PL[g] = *(const uint*)&pr[g * 128 + 2 * lane];                     \
        QL = *(const float4*)&Psum[(size_t)tkR * 4];                           \
    }                                                                          \
    {                                                                          \
        half8 af[4];                                                           \
        _Pragma("unroll")                                                      \
        for (int ks = 0; ks < 4; ++ks)                                         \
            af[ks] = *(const half8*)(hb + p16 * 256 +                          \
                         ((ks * 64 + (gq << 4)) ^ ((p16 & 7) << 4)));          \
        f32x4 acc[4];                                                          \
        _Pragma("unroll")                                                      \
        for (int tt = 0; tt < 4; ++tt) acc[tt] = (f32x4){0.f, 0.f, 0.f, 0.f};  \
        _Pragma("unroll")                                                      \
        for (int tt = 0; tt < 4; ++tt) {                                       \
            _Pragma("unroll")                                                  \
            for (int ks = 0; ks < 4; ++ks)                                     \
                acc[tt] = __builtin_amdgcn_mfma_f32_16x16x32_f16(              \
                    af[ks], bfrag[tt][ks], acc[tt], 0, 0, 0);                  \
        }                                                                      \
        if (wv == 7) {  /* gate row-sums for the mean trick */                 \
            f32x4 acc_s = (f32x4){0.f, 0.f, 0.f, 0.f};                         \
            _Pragma("unroll")                                                  \
            for (int ks = 0; ks < 4; ++ks)                                     \
                acc_s = __builtin_amdgcn_mfma_f32_16x16x32_f16(                \
                    af[ks], bsum[ks], acc_s, 0, 0, 0);                         \
            if (lane < 4) {                                                    \
                sm_lds[0][lane] = acc_s[0]; sm_lds[1][lane] = acc_s[1];        \
                sm_lds[2][lane] = acc_s[2]; sm_lds[3][lane] = acc_s[3];        \
            }                                                                  \
        }                                                                      \
        if (lane < 16) {                                                       \
            _Pragma("unroll")                                                  \
            for (int tt = 0; tt < 4; ++tt) {                                   \
                const int col = wv * 64 + tt * 16 + p16;                       \
                _Pragma("unroll")                                              \
                for (int r = 0; r < 4; ++r) z_lds[r][col] = acc[tt][r];        \
            }                                                                  \
        }                                                                      \
    }                                                                          \
    lds_barrier();   /* z + sm staged */                                       \
    /* ---- L phase: waves 0-3, row wv, hdims 2*lane, 2*lane+1 ---- */         \
    if (wv < 4) {                                                              \
        tkR = xtok[wv][((TSTEP) + 4 < Tt) ? (TSTEP) + 4 : Tt - 1];             \
        float2 zi[4];                                                          \
        _Pragma("unroll")                                                      \
        for (int g = 0; g < 4; ++g) {                                          \
            union { uint u; _Float16 h[2]; } pk; pk.u = PC[g];                 \
            float2 zr = *(const float2*)&z_lds[wv][g * 128 + 2 * lane];        \
            zi[g].x = zr.x + (float)pk.h[0];                                   \
            zi[g].y = zr.y + (float)pk.h[1];                                   \
        }                                                                      \
        const float4 smv = *(const float4*)&sm_lds[wv][0];                     \
        float mean[4], rstd[4];                                                \
        {                                                                      \
            const float qs[4] = {QC.x, QC.y, QC.z, QC.w};                      \
            const float sv[4] = {smv.x, smv.y, smv.z, smv.w};                  \
            _Pragma("unroll")                                                  \
            for (int g = 0; g < 4; ++g)                                        \
                mean[g] = (qs[g] + sv[g]) * (1.0f / Hh);                       \
        }                                                                      \
        _Pragma("unroll")                                                      \
        for (int g = 0; g < 4; ++g) {                                          \
            float q = red64b(fmaf(zi[g].x, zi[g].x, zi[g].y * zi[g].y));       \
            float var = q * (1.0f / Hh) - mean[g] * mean[g];                   \
            rstd[g] = rsqrtf(var + EPS);                                       \
        }                                                                      \
        float2 nv[4];                                                          \
        _Pragma("unroll")                                                      \
        for (int g = 0; g < 4; ++g) {                                          \
            nv[g].x = (zi[g].x - mean[g]) * rstd[g] * gg[g].x + sg[g].x;       \
            nv[g].y = (zi[g].y - mean[g]) * rstd[g] * gg[g].y + sg[g].y;       \
        }                                                                      \
        const float sox = sigm(nv[3].x);                                       \
        const float soy = sigm(nv[3].y);                                       \
        c0 = c0 * sigm(nv[2].x + FBIAS) + sigm(nv[0].x) * fmaxf(nv[1].x, 0.f); \
        c1 = c1 * sigm(nv[2].y + FBIAS) + sigm(nv[0].y) * fmaxf(nv[1].y, 0.f); \
        float s2 = red64b(c0 + c1);                                            \
        float q2 = red64b(fmaf(c0, c0, c1 * c1));                              \
        const float m2 = s2 * (1.0f / Hh);                                     \
        const float v2 = q2 * (1.0f / Hh) - m2 * m2;                           \
        const float r2 = rsqrtf(v2 + EPS);                                     \
        const float lc0 = (c0 - m2) * r2 * gcell.x + scell.x;                  \
        const float lc1 = (c1 - m2) * r2 * gcell.y + scell.y;                  \
        const float h0 = fmaxf(lc0, 0.f) * sox;                                \
        const float h1 = fmaxf(lc1, 0.f) * soy;                                \
        {                                                                      \
            union { _Float16 hh2[2]; uint u; } pk;                             \
            pk.hh2[0] = (_Float16)h0; pk.hh2[1] = (_Float16)h1;                \
            *(uint*)(hb + wv * 256 + ((4 * lane) ^ ((wv & 7) << 4))) = pk.u;   \
        }                                                                      \
        *(float2*)&out[((size_t)row_g * Tt + (TSTEP)) * Hh + 2 * lane] =       \
            (float2){h0, h1};                                                  \
    }                                                                          \
    lds_barrier();   /* h ready */                                             \
}

__global__ __launch_bounds__(512, 1) void lstm_mfma7(
    const _Float16* __restrict__ P,    // [V, 4H] f16
    const float* __restrict__ Psum,    // [V, 4] f32
    const float* __restrict__ Wsum,    // [128, 4] f32
    const float* __restrict__ W,       // [E+H, 4H]
    const int*   __restrict__ x,       // [B, T]
    const float* __restrict__ gains,   // [5, H]
    const float* __restrict__ shifts,  // [5, H]
    float* __restrict__ out)           // [B, T, H]
{
    __shared__ __align__(16) float    z_lds[RPBLK][G4];   // 8 KB
    __shared__ __align__(16) _Float16 h_lds[16][Hh];      // 4 KB (swizzled)
    __shared__ __align__(16) int      xtok[RPBLK][Tt];    // 8 KB
    __shared__ __align__(16) float    sm_lds[4][4];       // gate row-sums

    const int tid  = threadIdx.x;
    const int wv   = tid >> 6;         // 0..7: MFMA col-slice; <4: L row
    const int lane = tid & 63;
    const int gq   = lane >> 4;
    const int p16  = lane & 15;
    const int bb   = blockIdx.x;

    // stage tokens for this block's 4 rows (2048 ints = 512 int4)
    {
        const int4* xs = (const int4*)(x + (size_t)bb * RPBLK * Tt);
        ((int4*)&xtok[0][0])[tid] = xs[tid];
    }
    // zero h tile
    {
        uint* hz = (uint*)h_lds;
        hz[tid] = 0u; hz[tid + 512] = 0u;
    }

    // Wh B-fragments: cols wv*64 + tt*16 + p16
    half8 bfrag[4][4];
    #pragma unroll
    for (int tt = 0; tt < 4; ++tt) {
        #pragma unroll
        for (int ks = 0; ks < 4; ++ks) {
            half8 h;
            #pragma unroll
            for (int j = 0; j < 8; ++j) {
                h[j] = (_Float16)W[(size_t)(Ee + ks * 32 + gq * 8 + j) * G4
                                   + wv * 64 + tt * 16 + p16];
            }
            bfrag[tt][ks] = h;
        }
    }

    // Wsum B-fragment (wave 7 only): col c holds Wsum[:, c&3]
    half8 bsum[4];
    #pragma unroll
    for (int ks = 0; ks < 4; ++ks) bsum[ks] = (half8){};
    if (wv == 7) {
        #pragma unroll
        for (int ks = 0; ks < 4; ++ks) {
            half8 h;
            #pragma unroll
            for (int j = 0; j < 8; ++j)
                h[j] = (_Float16)Wsum[(ks * 32 + gq * 8 + j) * 4 + (p16 & 3)];
            bsum[ks] = h;
        }
    }

    // LN params (only used by waves 0-3; in-bounds for all)
    float2 gg[4], sg[4];
    #pragma unroll
    for (int g = 0; g < 4; ++g) {
        gg[g] = *(const float2*)&gains[g * Hh + 2 * lane];
        sg[g] = *(const float2*)&shifts[g * Hh + 2 * lane];
    }
    const float2 gcell = *(const float2*)&gains[4 * Hh + 2 * lane];
    const float2 scell = *(const float2*)&shifts[4 * Hh + 2 * lane];

    const int row_g = bb * RPBLK + (wv & 3);

    float c0 = 0.f, c1 = 0.f;
    char* const hb = (char*)h_lds;

    __syncthreads();   // tokens + h staged

    // P prefetch prologue: steps 0..2; tkR = token for step 3 (waves 0-3)
    uint pA[4], pB[4], pC[4], pD[4];
    float4 qA, qB, qC, qD;
    int tkR = 0;
    if (wv < 4) {
        int tk0 = xtok[wv][0];
        int tk1 = xtok[wv][1];
        int tk2 = xtok[wv][2];
        tkR = xtok[wv][3];
        const _Float16* p0 = P + (size_t)tk0 * G4;
        const _Float16* p1 = P + (size_t)tk1 * G4;
        const _Float16* p2 = P + (size_t)tk2 * G4;
        #pragma unroll
        for (int g = 0; g < 4; ++g) {
            pA[g] = *(const uint*)&p0[g * 128 + 2 * lane];
            pB[g] = *(const uint*)&p1[g * 128 + 2 * lane];
            pC[g] = *(const uint*)&p2[g * 128 + 2 * lane];
        }
        qA = *(const float4*)&Psum[(size_t)tk0 * 4];
        qB = *(const float4*)&Psum[(size_t)tk1 * 4];
        qC = *(const float4*)&Psum[(size_t)tk2 * 4];
    }

    for (int t = 0; t < Tt; t += 4) {
        LSTM_STEP(t,     pA, qA, pD, qD)
        LSTM_STEP(t + 1, pB, qB, pA, qA)
        LSTM_STEP(t + 2, pC, qC, pB, qB)
        LSTM_STEP(t + 3, pD, qD, pC, qC)
    }
}

// ---------------------------------------------------------------------------
extern "C" void kernel_launch(void* const* d_in, const int* in_sizes, int n_in,
                              void* d_out, int out_size, void* d_ws, size_t ws_size,
                              hipStream_t stream) {
    const int*   x      = (const int*)d_in[0];
    const float* embed  = (const float*)d_in[1];
    const float* W      = (const float*)d_in[2];
    const float* gains  = (const float*)d_in[3];
    const float* shifts = (const float*)d_in[4];
    float* out = (float*)d_out;

    _Float16* P    = (_Float16*)d_ws;                               // 51.2 MB
    float*    Psum = (float*)((char*)d_ws + (size_t)Vv * G4 * 2);   // 800 KB
    float*    Wsum = (float*)((char*)Psum + (size_t)Vv * 4 * 4);    // 2 KB

    wsum_kernel<<<dim3(1), dim3(128), 0, stream>>>(W, Wsum);
    embed_proj_mfma<<<dim3(256), dim3(512), 0, stream>>>(embed, W, P, Psum);
    lstm_mfma7<<<dim3(LBLK), dim3(512), 0, stream>>>(P, Psum, Wsum, W, x,
                                                     gains, shifts, out);
}